// Round 2
// baseline (1281.580 us; speedup 1.0000x reference)
//
#include <hip/hip_runtime.h>
#include <hip/hip_bf16.h>

typedef __attribute__((ext_vector_type(8))) short short8;
typedef __attribute__((ext_vector_type(4))) float f32x4;
typedef __attribute__((ext_vector_type(4))) int   i32x4;
typedef __hip_bfloat16 bf16_t;

#define HH 224
#define WW 224
#define HWSZ (224*224)
#define NIMG 16

// x (N,Cin,224,224) f32  ->  xc [N][224][Cin/32][224][32] bf16
template<int CIN>
__global__ __launch_bounds__(256)
void prep_x(const float* __restrict__ x, bf16_t* __restrict__ xc) {
  constexpr int NCC = CIN/32;
  __shared__ float tile[32][225];   // +1 pad: column reads conflict-free
  int b = blockIdx.x;
  int cc = b % NCC; int h = (b/NCC) % HH; int n = b / (NCC*HH);
  const float* src = x + ((long)(n*CIN + cc*32))*HWSZ + (long)h*WW;
  for (int i = threadIdx.x; i < 32*WW; i += 256) {
    int ci = i / WW, w = i - ci*WW;
    tile[ci][w] = src[(long)ci*HWSZ + w];
  }
  __syncthreads();
  bf16_t* dst = xc + ((long)(n*HH + h)*NCC + cc)*(WW*32);
  for (int i = threadIdx.x; i < WW*32; i += 256) {
    int w = i >> 5, ci = i & 31;
    dst[i] = __float2bfloat16(tile[ci][w]);
  }
}

// w (Cout,Cin,3,3) f32 -> wb [t][co][ci] bf16,  t = kh*3+kw
__global__ __launch_bounds__(256)
void prep_w(const float* __restrict__ w, bf16_t* __restrict__ wb, int Cout, int Cin) {
  int idx = blockIdx.x*256 + threadIdx.x;
  if (idx >= 9*Cout*Cin) return;
  int ci = idx % Cin; int r = idx / Cin; int co = r % Cout; int t = r / Cout;
  wb[idx] = __float2bfloat16(w[((long)co*Cin + ci)*9 + t]);
}

// Implicit-GEMM 3x3 conv, stride1 pad1.
// in : [N][224][CIN/32][224][32] bf16
// wb : [9][COUT][CIN] bf16
// out: FINAL ? [N][COUT][224][224] f32 : [N][224][COUT/32][224][32] bf16
// Tile: 2 rows x 224 cols x 64 couts. 4 waves: wave = (row, col-half), 7Mx4N frags.
template<int CIN, int COUT, bool FINAL>
__global__ __launch_bounds__(256, 2)
void conv3x3(const bf16_t* __restrict__ in, const bf16_t* __restrict__ wb,
             void* __restrict__ outp)
{
  constexpr int NCC = CIN/32;
  // [4 rows][226 cols][32 ci] bf16, rows of 64B, XOR-swizzled
  __shared__ unsigned short lds_x[4*226*32];   // 57856 B

  const int tid  = threadIdx.x;
  const int lane = tid & 63;
  const int l15  = lane & 15;
  const int lk   = lane >> 4;
  const int wv   = tid >> 6;
  const int rw   = wv >> 1;        // tile row 0/1
  const int cb   = (wv & 1)*112;   // col base

  const int tile = blockIdx.x;     // 0 .. NIMG*112-1
  const int n    = tile / 112;
  const int h0   = (tile - n*112)*2;
  const int co0  = blockIdx.y * 64;

  f32x4 acc[7][4];
  #pragma unroll
  for (int m=0;m<7;++m)
    #pragma unroll
    for (int q=0;q<4;++q) acc[m][q] = (f32x4){0.f,0.f,0.f,0.f};

  const bf16_t* inb   = in + (long)n * ((long)HH*NCC*WW*32);
  const bf16_t* wlane = wb + (long)(co0 + l15)*CIN + lk*8;   // per-lane B base

  for (int c = 0; c < NCC; ++c) {
    __syncthreads();   // protect lds_x from previous chunk's readers
    // ---- stage X chunk c: rows h0-1..h0+2, cols -1..224 (zero pad), 32 ci ----
    #pragma unroll
    for (int i = 0; i < 4; ++i) {
      int hh = h0 - 1 + i;
      const char* rowp = (const char*)(inb + ((long)hh*NCC + c)*(WW*32));
      bool rowok = (hh >= 0) & (hh < HH);
      for (int off = tid*16; off < 226*64; off += 256*16) {
        int j = off >> 6;          // lds col 0..225 -> image col j-1
        int wcol = j - 1;
        i32x4 v = (i32x4){0,0,0,0};
        if (rowok && (unsigned)wcol < (unsigned)WW)
          v = *(const i32x4*)(rowp + wcol*64 + (off & 63));
        int a = i*14464 + off;
        a ^= ((a>>7)&3)<<4;        // bank swizzle
        *(i32x4*)((char*)lds_x + a) = v;
      }
    }
    // prefetch tap-0 B frags (global/L2) while staging drains
    const bf16_t* wc = wlane + c*32;
    short8 bf[4];
    #pragma unroll
    for (int q=0;q<4;++q)
      bf[q] = *(const short8*)(wc + (long)(q*16)*CIN);
    __syncthreads();

    for (int t = 0; t < 9; ++t) {
      short8 bfn[4];
      if (t < 8) {                 // prefetch next tap's B frags
        #pragma unroll
        for (int q=0;q<4;++q)
          bfn[q] = *(const short8*)(wc + (long)((t+1)*COUT + q*16)*CIN);
      }
      const int dh = t/3, dw = t - (t/3)*3;
      const int arow = (rw + dh)*226;
      #pragma unroll
      for (int m=0;m<7;++m) {
        int a = (arow + cb + m*16 + l15 + dw)*64 + lk*16;
        a ^= ((a>>7)&3)<<4;
        short8 af = *(const short8*)((const char*)lds_x + a);
        #pragma unroll
        for (int q=0;q<4;++q)
          acc[m][q] = __builtin_amdgcn_mfma_f32_16x16x32_bf16(af, bf[q], acc[m][q], 0,0,0);
      }
      if (t < 8) {
        #pragma unroll
        for (int q=0;q<4;++q) bf[q] = bfn[q];
      }
    }
  }

  // ---- epilogue ----  D: col(lane&15)=co, row(lk*4+j)=pixel
  const int orow = h0 + rw;
  if (!FINAL) {
    bf16_t* out = (bf16_t*)outp;
    long ob = ((long)(n*HH + orow)*(COUT/32))*(WW*32);
    #pragma unroll
    for (int m=0;m<7;++m) {
      #pragma unroll
      for (int q=0;q<4;++q) {
        int co = co0 + q*16 + l15;
        long base = ob + ((long)(co>>5)*WW)*32 + (co & 31);
        int col = cb + m*16 + lk*4;
        #pragma unroll
        for (int jj=0;jj<4;++jj)
          out[base + (long)(col+jj)*32] = __float2bfloat16(acc[m][q][jj]);
      }
    }
  } else {
    float* out = (float*)outp;
    #pragma unroll
    for (int m=0;m<7;++m) {
      #pragma unroll
      for (int q=0;q<4;++q) {
        int co = co0 + q*16 + l15;
        int col = cb + m*16 + lk*4;
        *(f32x4*)(out + ((long)(n*COUT + co)*HH + orow)*WW + col) = acc[m][q];
      }
    }
  }
}

extern "C" void kernel_launch(void* const* d_in, const int* in_sizes, int n_in,
                              void* d_out, int out_size, void* d_ws, size_t ws_size,
                              hipStream_t stream) {
  (void)in_sizes; (void)n_in; (void)out_size; (void)ws_size;
  const float* x  = (const float*)d_in[0];
  const float* w1 = (const float*)d_in[1];
  const float* w2 = (const float*)d_in[2];
  const float* w3 = (const float*)d_in[3];

  // Buffer plan (peak d_ws use = 196.6 MiB):
  //   SB = one full 128-ch bf16 activation tensor = 205,520,896 B
  //   d_out (same byte size as SB!) doubles as a1 (conv1 output, bf16)
  //   ws[0..SB)        : xc (conv1 input, 64ch -> uses first half) then a2 (conv2 out)
  //   ws[SB.. )        : packed weights (589,824 B)
  const size_t SB = (size_t)NIMG*HH*WW*128*2;   // 205,520,896 B
  char* ws = (char*)d_ws;
  bf16_t* bufA = (bf16_t*)ws;            // xc (conv1 in), later a2 (conv2 out)
  bf16_t* a1   = (bf16_t*)d_out;         // conv1 out lives in d_out until conv3
  bf16_t* wb1  = (bf16_t*)(ws + SB);
  bf16_t* wb2  = wb1 + 9*128*64;
  bf16_t* wb3  = wb2 + 9*128*128;

  prep_x<64><<<NIMG*HH*2, 256, 0, stream>>>(x, bufA);
  prep_w<<<(9*128*64 + 255)/256, 256, 0, stream>>>(w1, wb1, 128, 64);
  prep_w<<<(9*128*128 + 255)/256, 256, 0, stream>>>(w2, wb2, 128, 128);
  prep_w<<<(9*64*128 + 255)/256, 256, 0, stream>>>(w3, wb3, 64, 128);

  conv3x3<64,128,false><<<dim3(NIMG*112, 2), 256, 0, stream>>>(bufA, wb1, a1);
  conv3x3<128,128,false><<<dim3(NIMG*112, 2), 256, 0, stream>>>(a1, wb2, bufA);
  conv3x3<128,64,true ><<<dim3(NIMG*112, 1), 256, 0, stream>>>(bufA, wb3, (float*)d_out);
}